// Round 1
// 735.154 us; speedup vs baseline: 1.0495x; 1.0495x over previous
//
#include <hip/hip_runtime.h>
#include <math.h>

typedef __attribute__((ext_vector_type(8))) short bf16x8;
typedef __attribute__((ext_vector_type(4))) float f32x4;
typedef __attribute__((ext_vector_type(4))) _Float16 f16x4;

__device__ __forceinline__ unsigned short f2bf(float f) {
    unsigned int u = __float_as_uint(f);
    unsigned int r = (u + 0x7FFF + ((u >> 16) & 1)) >> 16;  // RNE
    return (unsigned short)r;
}
__device__ __forceinline__ float bf2f(unsigned short h) {
    return __uint_as_float((unsigned int)h << 16);
}
__device__ __forceinline__ void split_bf(float x, unsigned short& hi, unsigned short& lo) {
    hi = f2bf(x);
    lo = f2bf(x - bf2f(hi));
}

// ---------------- CSR build ----------------

__global__ void k_hist(const int* __restrict__ dst, int* __restrict__ deg, int e) {
    int t = blockIdx.x * 256 + threadIdx.x;
    if (t < e) atomicAdd(&deg[dst[t]], 1);
}

__global__ void k_scan1(const int* __restrict__ deg, int* __restrict__ tmp,
                        int* __restrict__ bsum, int n) {
    __shared__ int s[1024];
    int t = threadIdx.x;
    int g = blockIdx.x * 1024 + t;
    int v = (g < n) ? deg[g] : 0;
    s[t] = v;
    __syncthreads();
    for (int off = 1; off < 1024; off <<= 1) {
        int u = (t >= off) ? s[t - off] : 0;
        __syncthreads();
        s[t] += u;
        __syncthreads();
    }
    if (g < n) tmp[g] = s[t];
    if (t == 1023) bsum[blockIdx.x] = s[t];
}

__global__ void k_scan2(int* bsum, int nb) {
    int acc = 0;
    for (int b = 0; b < nb; ++b) { int v = bsum[b]; bsum[b] = acc; acc += v; }
}

__global__ void k_scan3(const int* __restrict__ deg, const int* __restrict__ tmp,
                        const int* __restrict__ bsum, int* __restrict__ rowptr,
                        int* __restrict__ cursor, int n) {
    int g = blockIdx.x * 256 + threadIdx.x;
    if (g < n) {
        int incl = tmp[g] + bsum[g >> 10];
        rowptr[g + 1] = incl;
        cursor[g] = incl - deg[g];
        if (g == 0) rowptr[0] = 0;
    }
}

__global__ void k_scatter(const int* __restrict__ src, const int* __restrict__ dst,
                          int* __restrict__ cursor, int* __restrict__ csr, int e) {
    int t = blockIdx.x * 256 + threadIdx.x;
    if (t < e) {
        int d = dst[t];
        int pos = atomicAdd(&cursor[d], 1);
        csr[pos] = src[t];
    }
}

// ---------------- casts (split hi/lo) ----------------

__global__ void k_castx(const float* __restrict__ x, unsigned short* __restrict__ xhi,
                        unsigned short* __restrict__ xlo, int nvec) {
    int t = blockIdx.x * 256 + threadIdx.x;
    if (t < nvec) {
        float4 v = ((const float4*)x)[t];
        ushort4 h, l;
        split_bf(v.x, h.x, l.x);
        split_bf(v.y, h.y, l.y);
        split_bf(v.z, h.z, l.z);
        split_bf(v.w, h.w, l.w);
        ((ushort4*)xhi)[t] = h;
        ((ushort4*)xlo)[t] = l;
    }
}

__global__ void k_castw(const float* __restrict__ W, unsigned short* __restrict__ Whi,
                        unsigned short* __restrict__ Wlo, int K, int N) {
    int t = blockIdx.x * 256 + threadIdx.x;
    if (t < K * N) {
        int k = t / N, n = t - k * N;
        unsigned short h, l;
        split_bf(W[t], h, l);
        Whi[n * K + k] = h; Wlo[n * K + k] = l;
    }
}

// ------- split-bf16 MFMA GEMM (NT): C = A @ Bt^T, ~fp32 accuracy ----------
// Output written as fp16 (feeds gathers in agg; 11-bit mantissa is enough).
// swz=1: XCD-aware remap for Nb==4 so each XCD walks the 4 col-blocks of a
// row consecutively -> A-panel served from per-XCD L2 instead of 4x HBM.

#define LDP 40

__global__ __launch_bounds__(256) void k_gemm_split(const unsigned short* __restrict__ Ahi,
                                                    const unsigned short* __restrict__ Alo,
                                                    const unsigned short* __restrict__ Bhi,
                                                    const unsigned short* __restrict__ Blo,
                                                    _Float16* __restrict__ C,
                                                    int M, int Ncol, int K, int swz) {
    int bx = blockIdx.x, by = blockIdx.y;
    if (swz) {
        int v = bx;
        by = (v >> 3) & 3;
        bx = ((v >> 5) << 3) | (v & 7);
        if (bx >= ((M + 63) >> 6)) return;
    }
    __shared__ unsigned short Ash[64 * LDP];
    __shared__ unsigned short Asl[64 * LDP];
    __shared__ unsigned short Bsh[64 * LDP];
    __shared__ unsigned short Bsl[64 * LDP];
    int t = threadIdx.x;
    int w = t >> 6, lane = t & 63;
    int lrow = lane & 15, kgrp = (lane >> 4) * 8;
    int row0 = bx * 64, col0 = by * 64;
    int trow = t >> 2, tcol = (t & 3) * 8;

    f32x4 acc[4] = {{0.f, 0.f, 0.f, 0.f}, {0.f, 0.f, 0.f, 0.f},
                    {0.f, 0.f, 0.f, 0.f}, {0.f, 0.f, 0.f, 0.f}};

    for (int k0 = 0; k0 < K; k0 += 32) {
        uint4 ah = {0u,0u,0u,0u}, al = {0u,0u,0u,0u};
        uint4 bh = {0u,0u,0u,0u}, bl = {0u,0u,0u,0u};
        int gr = row0 + trow;
        if (gr < M) {
            ah = *(const uint4*)(Ahi + (size_t)gr * K + k0 + tcol);
            al = *(const uint4*)(Alo + (size_t)gr * K + k0 + tcol);
        }
        int gc = col0 + trow;
        if (gc < Ncol) {
            bh = *(const uint4*)(Bhi + (size_t)gc * K + k0 + tcol);
            bl = *(const uint4*)(Blo + (size_t)gc * K + k0 + tcol);
        }
        __syncthreads();
        *(uint4*)&Ash[trow * LDP + tcol] = ah;
        *(uint4*)&Asl[trow * LDP + tcol] = al;
        *(uint4*)&Bsh[trow * LDP + tcol] = bh;
        *(uint4*)&Bsl[trow * LDP + tcol] = bl;
        __syncthreads();
        bf16x8 vbh = *(const bf16x8*)&Bsh[(w * 16 + lrow) * LDP + kgrp];
        bf16x8 vbl = *(const bf16x8*)&Bsl[(w * 16 + lrow) * LDP + kgrp];
        #pragma unroll
        for (int mt = 0; mt < 4; ++mt) {
            bf16x8 vah = *(const bf16x8*)&Ash[(mt * 16 + lrow) * LDP + kgrp];
            bf16x8 val = *(const bf16x8*)&Asl[(mt * 16 + lrow) * LDP + kgrp];
            acc[mt] = __builtin_amdgcn_mfma_f32_16x16x32_bf16(vah, vbh, acc[mt], 0, 0, 0);
            acc[mt] = __builtin_amdgcn_mfma_f32_16x16x32_bf16(val, vbh, acc[mt], 0, 0, 0);
            acc[mt] = __builtin_amdgcn_mfma_f32_16x16x32_bf16(vah, vbl, acc[mt], 0, 0, 0);
        }
    }

    int ocol = col0 + w * 16 + lrow;
    if (ocol < Ncol) {
        int orow = (lane >> 4) * 4;
        #pragma unroll
        for (int mt = 0; mt < 4; ++mt) {
            #pragma unroll
            for (int r = 0; r < 4; ++r) {
                int m = row0 + mt * 16 + orow + r;
                if (m < M) C[(size_t)m * Ncol + ocol] = (_Float16)acc[mt][r];
            }
        }
    }
}

static inline void gemm_split(const unsigned short* Ah, const unsigned short* Al,
                              const unsigned short* Bh, const unsigned short* Bl,
                              _Float16* C, int M, int Ncol, int K, hipStream_t st) {
    int Mb = (M + 63) / 64, Nb = (Ncol + 63) / 64;
    if (Nb == 4) {
        int G = (Mb + 7) / 8;   // padded; kernel guards bx>=Mb
        k_gemm_split<<<dim3(G * 32, 1), 256, 0, st>>>(Ah, Al, Bh, Bl, C, M, Ncol, K, 1);
    } else {
        k_gemm_split<<<dim3(Mb, Nb), 256, 0, st>>>(Ah, Al, Bh, Bl, C, M, Ncol, K, 0);
    }
}

// ---------------- attention scores: el/er [N,H] ----------------

template <int H, int D>
__global__ __launch_bounds__(256) void k_attn(const _Float16* __restrict__ feat,
                                              const float* __restrict__ al,
                                              const float* __restrict__ ar,
                                              float* __restrict__ el,
                                              float* __restrict__ er, int n) {
    int gw = blockIdx.x * 4 + (threadIdx.x >> 6);
    int lane = threadIdx.x & 63;
    int i = gw / H, h = gw % H;
    if (i >= n) return;
    float f = (lane < D) ? (float)feat[i * (H * D) + h * D + lane] : 0.f;
    float wl = (lane < D) ? al[h * D + lane] : 0.f;
    float wr = (lane < D) ? ar[h * D + lane] : 0.f;
    float pl = f * wl, pr = f * wr;
    #pragma unroll
    for (int off = 32; off; off >>= 1) {
        pl += __shfl_xor(pl, off);
        pr += __shfl_xor(pr, off);
    }
    if (lane == 0) {
        el[i * H + h] = pl;
        er[i * H + h] = pr;
    }
}

__device__ __forceinline__ float lrelu(float v) { return v > 0.f ? v : 0.2f * v; }

// ---------------- H=4 aggregation: ONE WAVE per dst node ------------------
// Single-pass ONLINE softmax (running max + accumulator rescale; rescale is
// exp(0)=1 exactly once the max settles). LDS stages pre-multiplied byte
// offsets (src*512) and alpha transposed [h][16] so the FMA stage reads
// float4 alpha per 4 edges and issues 4 gather loads before consuming.
template <int ACT, int SPLITOUT>
__global__ __launch_bounds__(256) void k_agg4(const int* __restrict__ rowptr,
                                              const int* __restrict__ csr,
                                              const float* __restrict__ el,
                                              const float* __restrict__ er,
                                              const _Float16* __restrict__ feat,
                                              unsigned short* __restrict__ ohi,
                                              unsigned short* __restrict__ olo,
                                              float* __restrict__ ofp, int n) {
    __shared__ int   s_off[4][16];
    __shared__ float s_ex[4][64];
    int w = threadIdx.x >> 6;
    int lane = threadIdx.x & 63;
    int i = blockIdx.x * 4 + w;
    if (i >= n) return;
    int s0 = rowptr[i], s1 = rowptr[i + 1];
    int deg = s1 - s0;
    int eidx = lane >> 2, h = lane & 3;  // exp-stage role
    int hh = lane >> 4;                  // FMA/output-stage head
    float erh = er[i * 4 + h];
    const char* featLane = (const char*)feat + (lane << 3);

    float den = 0.f;
    float a0 = 0.f, a1 = 0.f, a2 = 0.f, a3 = 0.f;

    auto fma_chunk = [&](int cnt) {
        const float* exrow = &s_ex[w][hh << 4];
        int j = 0;
        for (; j + 4 <= cnt; j += 4) {
            int4   oj = *(const int4*)&s_off[w][j];
            float4 xj = *(const float4*)&exrow[j];
            f16x4 f0 = *(const f16x4*)(featLane + oj.x);
            f16x4 f1 = *(const f16x4*)(featLane + oj.y);
            f16x4 f2 = *(const f16x4*)(featLane + oj.z);
            f16x4 f3 = *(const f16x4*)(featLane + oj.w);
            a0 = fmaf(xj.x, (float)f0.x, fmaf(xj.y, (float)f1.x,
                 fmaf(xj.z, (float)f2.x, fmaf(xj.w, (float)f3.x, a0))));
            a1 = fmaf(xj.x, (float)f0.y, fmaf(xj.y, (float)f1.y,
                 fmaf(xj.z, (float)f2.y, fmaf(xj.w, (float)f3.y, a1))));
            a2 = fmaf(xj.x, (float)f0.z, fmaf(xj.y, (float)f1.z,
                 fmaf(xj.z, (float)f2.z, fmaf(xj.w, (float)f3.z, a2))));
            a3 = fmaf(xj.x, (float)f0.w, fmaf(xj.y, (float)f1.w,
                 fmaf(xj.z, (float)f2.w, fmaf(xj.w, (float)f3.w, a3))));
        }
        for (; j + 2 <= cnt; j += 2) {
            int o0 = s_off[w][j], o1 = s_off[w][j + 1];
            float x0 = exrow[j], x1 = exrow[j + 1];
            f16x4 f0 = *(const f16x4*)(featLane + o0);
            f16x4 f1 = *(const f16x4*)(featLane + o1);
            a0 = fmaf(x0, (float)f0.x, fmaf(x1, (float)f1.x, a0));
            a1 = fmaf(x0, (float)f0.y, fmaf(x1, (float)f1.y, a1));
            a2 = fmaf(x0, (float)f0.z, fmaf(x1, (float)f1.z, a2));
            a3 = fmaf(x0, (float)f0.w, fmaf(x1, (float)f1.w, a3));
        }
        for (; j < cnt; ++j) {
            int o = s_off[w][j];
            float x = exrow[j];
            f16x4 f0 = *(const f16x4*)(featLane + o);
            a0 = fmaf(x, (float)f0.x, a0);
            a1 = fmaf(x, (float)f0.y, a1);
            a2 = fmaf(x, (float)f0.z, a2);
            a3 = fmaf(x, (float)f0.w, a3);
        }
    };

    if (deg <= 16) {
        int e = s0 + eidx;
        int s = 0;
        float v = -INFINITY;
        if (e < s1) {
            s = csr[e];
            v = lrelu(el[(s << 2) + h] + erh);
        }
        float m = v;
        #pragma unroll
        for (int off = 4; off < 64; off <<= 1) m = fmaxf(m, __shfl_xor(m, off));
        float ex = (e < s1) ? __expf(v - m) : 0.f;
        den = ex;
        if (h == 0) s_off[w][eidx] = s << 9;
        s_ex[w][(h << 4) + eidx] = ex;
        fma_chunk(deg);
    } else {
        float m = -INFINITY;
        for (int c = s0; c < s1; c += 16) {
            int e = c + eidx;
            int s = 0;
            float v = -INFINITY;
            if (e < s1) {
                s = csr[e];
                v = lrelu(el[(s << 2) + h] + erh);
            }
            float cm = v;
            #pragma unroll
            for (int off = 4; off < 64; off <<= 1) cm = fmaxf(cm, __shfl_xor(cm, off));
            float mn = fmaxf(m, cm);
            float scale = __expf(m - mn);  // exactly 1.0 when max unchanged; 0 on first chunk
            m = mn;
            float ex = (e < s1) ? __expf(v - mn) : 0.f;
            den = den * scale + ex;
            if (h == 0) s_off[w][eidx] = s << 9;
            s_ex[w][(h << 4) + eidx] = ex;
            float scl = __shfl(scale, hh);  // lanes 0..3 hold h=0..3
            a0 *= scl; a1 *= scl; a2 *= scl; a3 *= scl;
            fma_chunk(min(16, s1 - c));
        }
    }
    #pragma unroll
    for (int off = 4; off < 64; off <<= 1) den += __shfl_xor(den, off);
    float d = fmaxf(__shfl(den, hh), 1e-9f);

    float o0 = (deg > 0) ? a0 / d : 0.f;
    float o1 = (deg > 0) ? a1 / d : 0.f;
    float o2 = (deg > 0) ? a2 / d : 0.f;
    float o3 = (deg > 0) ? a3 / d : 0.f;
    if (ACT == 1) {
        o0 = o0 > 0.f ? o0 : (__expf(o0) - 1.f);
        o1 = o1 > 0.f ? o1 : (__expf(o1) - 1.f);
        o2 = o2 > 0.f ? o2 : (__expf(o2) - 1.f);
        o3 = o3 > 0.f ? o3 : (__expf(o3) - 1.f);
    }
    size_t base = (size_t)i * 256 + (lane << 2);
    if (SPLITOUT) {
        ushort4 vh, vl;
        split_bf(o0, vh.x, vl.x);
        split_bf(o1, vh.y, vl.y);
        split_bf(o2, vh.z, vl.z);
        split_bf(o3, vh.w, vl.w);
        *(ushort4*)&ohi[base] = vh;
        *(ushort4*)&olo[base] = vl;
    } else {
        float4 vo = {o0, o1, o2, o3};
        *(float4*)&ofp[base] = vo;
    }
}

// ---------------- H=1 aggregation (online softmax, byte-offset staging) ----

template <int D, int ACT, int SPLITOUT>
__global__ __launch_bounds__(256) void k_agg1(const int* __restrict__ rowptr,
                                              const int* __restrict__ csr,
                                              const float* __restrict__ el,
                                              const float* __restrict__ er,
                                              const _Float16* __restrict__ feat,
                                              unsigned short* __restrict__ ohi,
                                              unsigned short* __restrict__ olo,
                                              float* __restrict__ ofp, int n) {
    __shared__ int   s_off[4][64];
    __shared__ float s_ex[4][64];
    int w = threadIdx.x >> 6;
    int i = blockIdx.x * 4 + w;
    int lane = threadIdx.x & 63;
    if (i >= n) return;
    int s0 = rowptr[i], s1 = rowptr[i + 1];
    int deg = s1 - s0;
    float eri = er[i];
    bool act = lane < D;
    const char* featLane = (const char*)feat + lane * 2;

    float den = 0.f, acc = 0.f;

    auto fma_chunk = [&](int cnt) {
        int j = 0;
        for (; j + 4 <= cnt; j += 4) {
            int4   oj = *(const int4*)&s_off[w][j];
            float4 xj = *(const float4*)&s_ex[w][j];
            float f0 = act ? (float)*(const _Float16*)(featLane + oj.x) : 0.f;
            float f1 = act ? (float)*(const _Float16*)(featLane + oj.y) : 0.f;
            float f2 = act ? (float)*(const _Float16*)(featLane + oj.z) : 0.f;
            float f3 = act ? (float)*(const _Float16*)(featLane + oj.w) : 0.f;
            acc = fmaf(xj.x, f0, fmaf(xj.y, f1, fmaf(xj.z, f2, fmaf(xj.w, f3, acc))));
        }
        for (; j < cnt; ++j) {
            float f0 = act ? (float)*(const _Float16*)(featLane + s_off[w][j]) : 0.f;
            acc = fmaf(s_ex[w][j], f0, acc);
        }
    };

    if (deg <= 64) {
        int e = s0 + lane;
        int s = 0;
        float v = -INFINITY;
        if (e < s1) {
            s = csr[e];
            v = lrelu(el[s] + eri);
        }
        float m = v;
        #pragma unroll
        for (int off = 32; off; off >>= 1) m = fmaxf(m, __shfl_xor(m, off));
        float ex = (e < s1) ? __expf(v - m) : 0.f;
        den = ex;
        s_off[w][lane] = s * (D * 2);
        s_ex[w][lane] = ex;
        fma_chunk(deg);
    } else {
        float m = -INFINITY;
        for (int c = s0; c < s1; c += 64) {
            int e = c + lane;
            int s = 0;
            float v = -INFINITY;
            if (e < s1) {
                s = csr[e];
                v = lrelu(el[s] + eri);
            }
            float cm = v;
            #pragma unroll
            for (int off = 32; off; off >>= 1) cm = fmaxf(cm, __shfl_xor(cm, off));
            float mn = fmaxf(m, cm);
            float scale = __expf(m - mn);
            m = mn;
            float ex = (e < s1) ? __expf(v - mn) : 0.f;
            den = den * scale + ex;
            acc *= scale;
            s_off[w][lane] = s * (D * 2);
            s_ex[w][lane] = ex;
            fma_chunk(min(64, s1 - c));
        }
    }
    #pragma unroll
    for (int off = 32; off; off >>= 1) den += __shfl_xor(den, off);

    float o = (deg > 0) ? acc / fmaxf(den, 1e-9f) : 0.f;
    if (ACT == 1) o = o > 0.f ? o : (__expf(o) - 1.f);
    if (act) {
        if (SPLITOUT) {
            unsigned short oh, ol;
            split_bf(o, oh, ol);
            ohi[(size_t)i * D + lane] = oh;
            olo[(size_t)i * D + lane] = ol;
        } else {
            ofp[(size_t)i * D + lane] = o;
        }
    }
}

// ---------------- launch ----------------

extern "C" void kernel_launch(void* const* d_in, const int* in_sizes, int n_in,
                              void* d_out, int out_size, void* d_ws, size_t ws_size,
                              hipStream_t stream) {
    const float* x    = (const float*)d_in[0];
    const int*   src  = (const int*)d_in[1];
    const int*   dst  = (const int*)d_in[2];
    const float* W00  = (const float*)d_in[3];
    const float* a00l = (const float*)d_in[4];
    const float* a00r = (const float*)d_in[5];
    const float* W01  = (const float*)d_in[6];
    const float* a01l = (const float*)d_in[7];
    const float* a01r = (const float*)d_in[8];
    const float* W0f  = (const float*)d_in[9];
    const float* a0fl = (const float*)d_in[10];
    const float* a0fr = (const float*)d_in[11];
    const float* W10  = (const float*)d_in[12];
    const float* a10l = (const float*)d_in[13];
    const float* a10r = (const float*)d_in[14];
    const float* W1f  = (const float*)d_in[15];
    const float* a1fl = (const float*)d_in[16];
    const float* a1fr = (const float*)d_in[17];
    const float* W1o  = (const float*)d_in[18];
    const float* a1ol = (const float*)d_in[19];
    const float* a1or = (const float*)d_in[20];
    float* out = (float*)d_out;

    const int n = in_sizes[0] / 256;  // 50000
    const int e = in_sizes[1];        // 800000
    const int C = 40;

    char* p = (char*)d_ws;
    auto alloc = [&](size_t bytes) -> void* {
        void* r = (void*)p;
        p += (bytes + 255) & ~(size_t)255;
        return r;
    };
    int*   deg     = (int*)alloc((size_t)n * 4);
    int*   tmp     = (int*)alloc((size_t)n * 4);
    int*   bsum    = (int*)alloc(64 * 4);
    int*   rowptr  = (int*)alloc((size_t)(n + 1) * 4);
    int*   cursor  = (int*)alloc((size_t)n * 4);
    int*   csr     = (int*)alloc((size_t)e * 4);
    float* el      = (float*)alloc((size_t)n * 4 * 4);
    float* er      = (float*)alloc((size_t)n * 4 * 4);
    _Float16* feat = (_Float16*)alloc((size_t)n * 256 * 2 + 256);
    unsigned short* xhi = (unsigned short*)alloc((size_t)n * 256 * 2);
    unsigned short* xlo = (unsigned short*)alloc((size_t)n * 256 * 2);
    unsigned short* hhi = (unsigned short*)alloc((size_t)n * 256 * 2);
    unsigned short* hlo = (unsigned short*)alloc((size_t)n * 256 * 2);
    unsigned short* W00h = (unsigned short*)alloc(256 * 256 * 2);
    unsigned short* W00l = (unsigned short*)alloc(256 * 256 * 2);
    unsigned short* W01h = (unsigned short*)alloc(256 * 64 * 2);
    unsigned short* W01l = (unsigned short*)alloc(256 * 64 * 2);
    unsigned short* W0fh = (unsigned short*)alloc(64 * 40 * 2);
    unsigned short* W0fl = (unsigned short*)alloc(64 * 40 * 2);
    unsigned short* W10h = (unsigned short*)alloc(256 * 256 * 2);
    unsigned short* W10l = (unsigned short*)alloc(256 * 256 * 2);
    unsigned short* W1fh = (unsigned short*)alloc(256 * 64 * 2);
    unsigned short* W1fl = (unsigned short*)alloc(256 * 64 * 2);
    unsigned short* W1oh = (unsigned short*)alloc(64 * 40 * 2);
    unsigned short* W1ol = (unsigned short*)alloc(64 * 40 * 2);

    // ---- CSR build ----
    hipMemsetAsync(deg, 0, (size_t)n * 4, stream);
    k_hist<<<(e + 255) / 256, 256, 0, stream>>>(dst, deg, e);
    int nb = (n + 1023) / 1024;
    k_scan1<<<nb, 1024, 0, stream>>>(deg, tmp, bsum, n);
    k_scan2<<<1, 1, 0, stream>>>(bsum, nb);
    k_scan3<<<(n + 255) / 256, 256, 0, stream>>>(deg, tmp, bsum, rowptr, cursor, n);
    k_scatter<<<(e + 255) / 256, 256, 0, stream>>>(src, dst, cursor, csr, e);

    // ---- casts ----
    int nel = n * 256;
    k_castx<<<(nel / 4 + 255) / 256, 256, 0, stream>>>(x, xhi, xlo, nel / 4);
    k_castw<<<(256 * 256 + 255) / 256, 256, 0, stream>>>(W00, W00h, W00l, 256, 256);
    k_castw<<<(256 * 64 + 255) / 256, 256, 0, stream>>>(W01, W01h, W01l, 256, 64);
    k_castw<<<(64 * 40 + 255) / 256, 256, 0, stream>>>(W0f, W0fh, W0fl, 64, 40);
    k_castw<<<(256 * 256 + 255) / 256, 256, 0, stream>>>(W10, W10h, W10l, 256, 256);
    k_castw<<<(256 * 64 + 255) / 256, 256, 0, stream>>>(W1f, W1fh, W1fl, 256, 64);
    k_castw<<<(64 * 40 + 255) / 256, 256, 0, stream>>>(W1o, W1oh, W1ol, 64, 40);

    int gw4 = (n * 4 + 3) / 4;
    int gw1 = (n + 3) / 4;

    // ---- branch 0 ----
    gemm_split(xhi, xlo, W00h, W00l, feat, n, 256, 256, stream);
    k_attn<4, 64><<<gw4, 256, 0, stream>>>(feat, a00l, a00r, el, er, n);
    k_agg4<1, 1><<<gw1, 256, 0, stream>>>(rowptr, csr, el, er, feat, hhi, hlo, nullptr, n);

    gemm_split(hhi, hlo, W01h, W01l, feat, n, 64, 256, stream);
    k_attn<1, 64><<<gw1, 256, 0, stream>>>(feat, a01l, a01r, el, er, n);
    k_agg1<64, 1, 1><<<gw1, 256, 0, stream>>>(rowptr, csr, el, er, feat, hhi, hlo, nullptr, n);

    gemm_split(hhi, hlo, W0fh, W0fl, feat, n, C, 64, stream);
    k_attn<1, 40><<<gw1, 256, 0, stream>>>(feat, a0fl, a0fr, el, er, n);
    k_agg1<40, 0, 0><<<gw1, 256, 0, stream>>>(rowptr, csr, el, er, feat, nullptr, nullptr, out, n);

    // ---- branch 1 ----
    gemm_split(xhi, xlo, W10h, W10l, feat, n, 256, 256, stream);
    k_attn<4, 64><<<gw4, 256, 0, stream>>>(feat, a10l, a10r, el, er, n);
    k_agg4<1, 1><<<gw1, 256, 0, stream>>>(rowptr, csr, el, er, feat, hhi, hlo, nullptr, n);

    gemm_split(hhi, hlo, W1fh, W1fl, feat, n, 64, 256, stream);
    k_attn<1, 64><<<gw1, 256, 0, stream>>>(feat, a1fl, a1fr, el, er, n);
    k_agg1<64, 0, 1><<<gw1, 256, 0, stream>>>(rowptr, csr, el, er, feat, hhi, hlo, nullptr, n);

    gemm_split(hhi, hlo, W1oh, W1ol, feat, n, C, 64, stream);
    k_attn<1, 40><<<gw1, 256, 0, stream>>>(feat, a1ol, a1or, el, er, n);
    k_agg1<40, 1, 0><<<gw1, 256, 0, stream>>>(rowptr, csr, el, er, feat, nullptr, nullptr,
                                              out + (size_t)n * C, n);
}

// Round 2
// 709.413 us; speedup vs baseline: 1.0875x; 1.0363x over previous
//
#include <hip/hip_runtime.h>
#include <math.h>

typedef __attribute__((ext_vector_type(8))) short bf16x8;
typedef __attribute__((ext_vector_type(4))) float f32x4;
typedef __attribute__((ext_vector_type(4))) _Float16 f16x4;

// f32 += f16(lo/hi half of packed dword) * f32  -- exact, single VOP3P instr
#define FMAMIX_LO(acc, pk, s) \
    asm("v_fma_mix_f32 %0, %1, %2, %0 op_sel:[0,0,0] op_sel_hi:[1,0,0]" \
        : "+v"(acc) : "v"(pk), "v"(s))
#define FMAMIX_HI(acc, pk, s) \
    asm("v_fma_mix_f32 %0, %1, %2, %0 op_sel:[1,0,0] op_sel_hi:[1,0,0]" \
        : "+v"(acc) : "v"(pk), "v"(s))

__device__ __forceinline__ unsigned short f2bf(float f) {
    unsigned int u = __float_as_uint(f);
    unsigned int r = (u + 0x7FFF + ((u >> 16) & 1)) >> 16;  // RNE
    return (unsigned short)r;
}
__device__ __forceinline__ float bf2f(unsigned short h) {
    return __uint_as_float((unsigned int)h << 16);
}
__device__ __forceinline__ void split_bf(float x, unsigned short& hi, unsigned short& lo) {
    hi = f2bf(x);
    lo = f2bf(x - bf2f(hi));
}

// ---------------- CSR build ----------------

__global__ void k_hist(const int* __restrict__ dst, int* __restrict__ deg, int e) {
    int t = blockIdx.x * 256 + threadIdx.x;
    if (t < e) atomicAdd(&deg[dst[t]], 1);
}

__global__ void k_scan1(const int* __restrict__ deg, int* __restrict__ tmp,
                        int* __restrict__ bsum, int n) {
    __shared__ int s[1024];
    int t = threadIdx.x;
    int g = blockIdx.x * 1024 + t;
    int v = (g < n) ? deg[g] : 0;
    s[t] = v;
    __syncthreads();
    for (int off = 1; off < 1024; off <<= 1) {
        int u = (t >= off) ? s[t - off] : 0;
        __syncthreads();
        s[t] += u;
        __syncthreads();
    }
    if (g < n) tmp[g] = s[t];
    if (t == 1023) bsum[blockIdx.x] = s[t];
}

__global__ void k_scan2(int* bsum, int nb) {
    int acc = 0;
    for (int b = 0; b < nb; ++b) { int v = bsum[b]; bsum[b] = acc; acc += v; }
}

__global__ void k_scan3(const int* __restrict__ deg, const int* __restrict__ tmp,
                        const int* __restrict__ bsum, int* __restrict__ rowptr,
                        int* __restrict__ cursor, int n) {
    int g = blockIdx.x * 256 + threadIdx.x;
    if (g < n) {
        int incl = tmp[g] + bsum[g >> 10];
        rowptr[g + 1] = incl;
        cursor[g] = incl - deg[g];
        if (g == 0) rowptr[0] = 0;
    }
}

__global__ void k_scatter(const int* __restrict__ src, const int* __restrict__ dst,
                          int* __restrict__ cursor, int* __restrict__ csr, int e) {
    int t = blockIdx.x * 256 + threadIdx.x;
    if (t < e) {
        int d = dst[t];
        int pos = atomicAdd(&cursor[d], 1);
        csr[pos] = src[t];
    }
}

// ---------------- casts (split hi/lo) ----------------

__global__ void k_castx(const float* __restrict__ x, unsigned short* __restrict__ xhi,
                        unsigned short* __restrict__ xlo, int nvec) {
    int t = blockIdx.x * 256 + threadIdx.x;
    if (t < nvec) {
        float4 v = ((const float4*)x)[t];
        ushort4 h, l;
        split_bf(v.x, h.x, l.x);
        split_bf(v.y, h.y, l.y);
        split_bf(v.z, h.z, l.z);
        split_bf(v.w, h.w, l.w);
        ((ushort4*)xhi)[t] = h;
        ((ushort4*)xlo)[t] = l;
    }
}

__global__ void k_castw(const float* __restrict__ W, unsigned short* __restrict__ Whi,
                        unsigned short* __restrict__ Wlo, int K, int N) {
    int t = blockIdx.x * 256 + threadIdx.x;
    if (t < K * N) {
        int k = t / N, n = t - k * N;
        unsigned short h, l;
        split_bf(W[t], h, l);
        Whi[n * K + k] = h; Wlo[n * K + k] = l;
    }
}

// ------- split-bf16 MFMA GEMM (NT): C = A @ Bt^T, ~fp32 accuracy ----------
// Output written as fp16 (feeds gathers in agg; 11-bit mantissa is enough).

#define LDP 40

// 64x64-tile kernel (small N: 64, 40)
__global__ __launch_bounds__(256) void k_gemm_split(const unsigned short* __restrict__ Ahi,
                                                    const unsigned short* __restrict__ Alo,
                                                    const unsigned short* __restrict__ Bhi,
                                                    const unsigned short* __restrict__ Blo,
                                                    _Float16* __restrict__ C,
                                                    int M, int Ncol, int K) {
    int bx = blockIdx.x, by = blockIdx.y;
    __shared__ unsigned short Ash[64 * LDP];
    __shared__ unsigned short Asl[64 * LDP];
    __shared__ unsigned short Bsh[64 * LDP];
    __shared__ unsigned short Bsl[64 * LDP];
    int t = threadIdx.x;
    int w = t >> 6, lane = t & 63;
    int lrow = lane & 15, kgrp = (lane >> 4) * 8;
    int row0 = bx * 64, col0 = by * 64;
    int trow = t >> 2, tcol = (t & 3) * 8;

    f32x4 acc[4] = {{0.f, 0.f, 0.f, 0.f}, {0.f, 0.f, 0.f, 0.f},
                    {0.f, 0.f, 0.f, 0.f}, {0.f, 0.f, 0.f, 0.f}};

    for (int k0 = 0; k0 < K; k0 += 32) {
        uint4 ah = {0u,0u,0u,0u}, al = {0u,0u,0u,0u};
        uint4 bh = {0u,0u,0u,0u}, bl = {0u,0u,0u,0u};
        int gr = row0 + trow;
        if (gr < M) {
            ah = *(const uint4*)(Ahi + (size_t)gr * K + k0 + tcol);
            al = *(const uint4*)(Alo + (size_t)gr * K + k0 + tcol);
        }
        int gc = col0 + trow;
        if (gc < Ncol) {
            bh = *(const uint4*)(Bhi + (size_t)gc * K + k0 + tcol);
            bl = *(const uint4*)(Blo + (size_t)gc * K + k0 + tcol);
        }
        __syncthreads();
        *(uint4*)&Ash[trow * LDP + tcol] = ah;
        *(uint4*)&Asl[trow * LDP + tcol] = al;
        *(uint4*)&Bsh[trow * LDP + tcol] = bh;
        *(uint4*)&Bsl[trow * LDP + tcol] = bl;
        __syncthreads();
        bf16x8 vbh = *(const bf16x8*)&Bsh[(w * 16 + lrow) * LDP + kgrp];
        bf16x8 vbl = *(const bf16x8*)&Bsl[(w * 16 + lrow) * LDP + kgrp];
        #pragma unroll
        for (int mt = 0; mt < 4; ++mt) {
            bf16x8 vah = *(const bf16x8*)&Ash[(mt * 16 + lrow) * LDP + kgrp];
            bf16x8 val = *(const bf16x8*)&Asl[(mt * 16 + lrow) * LDP + kgrp];
            acc[mt] = __builtin_amdgcn_mfma_f32_16x16x32_bf16(vah, vbh, acc[mt], 0, 0, 0);
            acc[mt] = __builtin_amdgcn_mfma_f32_16x16x32_bf16(val, vbh, acc[mt], 0, 0, 0);
            acc[mt] = __builtin_amdgcn_mfma_f32_16x16x32_bf16(vah, vbl, acc[mt], 0, 0, 0);
        }
    }

    int ocol = col0 + w * 16 + lrow;
    if (ocol < Ncol) {
        int orow = (lane >> 4) * 4;
        #pragma unroll
        for (int mt = 0; mt < 4; ++mt) {
            #pragma unroll
            for (int r = 0; r < 4; ++r) {
                int m = row0 + mt * 16 + orow + r;
                if (m < M) C[(size_t)m * Ncol + ocol] = (_Float16)acc[mt][r];
            }
        }
    }
}

// 128x128-tile kernel for Ncol==256 (2 col-blocks). 4 waves in 2x2 quadrants,
// 48 MFMA / wave / K-step. Bijective m204 XCD-chunk swizzle so the two
// col-blocks of neighboring row-tiles share an XCD's L2 (A-panel reuse).
__global__ __launch_bounds__(256) void k_gemm128(const unsigned short* __restrict__ Ahi,
                                                 const unsigned short* __restrict__ Alo,
                                                 const unsigned short* __restrict__ Bhi,
                                                 const unsigned short* __restrict__ Blo,
                                                 _Float16* __restrict__ C,
                                                 int M, int Ncol, int K) {
    int Mb = (M + 127) >> 7;
    int nwg = Mb * 2;
    int v = blockIdx.x;
    int q = nwg >> 3, r = nwg & 7;
    int xcd = v & 7, idx = v >> 3;
    int wg = (xcd < r ? xcd * (q + 1) : r * (q + 1) + (xcd - r) * q) + idx;
    int bx = wg >> 1, by = wg & 1;
    int row0 = bx * 128, col0 = by * 128;

    __shared__ unsigned short Ash[128 * LDP];
    __shared__ unsigned short Asl[128 * LDP];
    __shared__ unsigned short Bsh[128 * LDP];
    __shared__ unsigned short Bsl[128 * LDP];

    int t = threadIdx.x;
    int w = t >> 6, lane = t & 63;
    int wr = w >> 1, wc = w & 1;
    int lrow = lane & 15, kgrp = (lane >> 4) * 8;
    int trow = t >> 1, tcol = (t & 1) * 16;

    f32x4 acc[4][4];
    #pragma unroll
    for (int mt = 0; mt < 4; ++mt)
        #pragma unroll
        for (int nt = 0; nt < 4; ++nt)
            acc[mt][nt] = (f32x4){0.f, 0.f, 0.f, 0.f};

    for (int k0 = 0; k0 < K; k0 += 32) {
        uint4 a0 = {0u,0u,0u,0u}, a1 = {0u,0u,0u,0u};
        uint4 l0 = {0u,0u,0u,0u}, l1 = {0u,0u,0u,0u};
        uint4 b0 = {0u,0u,0u,0u}, b1 = {0u,0u,0u,0u};
        uint4 m0 = {0u,0u,0u,0u}, m1 = {0u,0u,0u,0u};
        int gr = row0 + trow;
        if (gr < M) {
            const unsigned short* pa = Ahi + (size_t)gr * K + k0 + tcol;
            const unsigned short* pl = Alo + (size_t)gr * K + k0 + tcol;
            a0 = *(const uint4*)pa;       a1 = *(const uint4*)(pa + 8);
            l0 = *(const uint4*)pl;       l1 = *(const uint4*)(pl + 8);
        }
        int gc = col0 + trow;
        if (gc < Ncol) {
            const unsigned short* pb = Bhi + (size_t)gc * K + k0 + tcol;
            const unsigned short* pm = Blo + (size_t)gc * K + k0 + tcol;
            b0 = *(const uint4*)pb;       b1 = *(const uint4*)(pb + 8);
            m0 = *(const uint4*)pm;       m1 = *(const uint4*)(pm + 8);
        }
        __syncthreads();
        *(uint4*)&Ash[trow * LDP + tcol]     = a0;
        *(uint4*)&Ash[trow * LDP + tcol + 8] = a1;
        *(uint4*)&Asl[trow * LDP + tcol]     = l0;
        *(uint4*)&Asl[trow * LDP + tcol + 8] = l1;
        *(uint4*)&Bsh[trow * LDP + tcol]     = b0;
        *(uint4*)&Bsh[trow * LDP + tcol + 8] = b1;
        *(uint4*)&Bsl[trow * LDP + tcol]     = m0;
        *(uint4*)&Bsl[trow * LDP + tcol + 8] = m1;
        __syncthreads();

        bf16x8 vbh[4], vbl[4];
        #pragma unroll
        for (int nt = 0; nt < 4; ++nt) {
            vbh[nt] = *(const bf16x8*)&Bsh[(wc * 64 + nt * 16 + lrow) * LDP + kgrp];
            vbl[nt] = *(const bf16x8*)&Bsl[(wc * 64 + nt * 16 + lrow) * LDP + kgrp];
        }
        #pragma unroll
        for (int mt = 0; mt < 4; ++mt) {
            bf16x8 vah = *(const bf16x8*)&Ash[(wr * 64 + mt * 16 + lrow) * LDP + kgrp];
            bf16x8 val = *(const bf16x8*)&Asl[(wr * 64 + mt * 16 + lrow) * LDP + kgrp];
            #pragma unroll
            for (int nt = 0; nt < 4; ++nt) {
                acc[mt][nt] = __builtin_amdgcn_mfma_f32_16x16x32_bf16(vah, vbh[nt], acc[mt][nt], 0, 0, 0);
                acc[mt][nt] = __builtin_amdgcn_mfma_f32_16x16x32_bf16(val, vbh[nt], acc[mt][nt], 0, 0, 0);
                acc[mt][nt] = __builtin_amdgcn_mfma_f32_16x16x32_bf16(vah, vbl[nt], acc[mt][nt], 0, 0, 0);
            }
        }
    }

    int orow = (lane >> 4) * 4;
    #pragma unroll
    for (int mt = 0; mt < 4; ++mt) {
        #pragma unroll
        for (int nt = 0; nt < 4; ++nt) {
            int oc = col0 + wc * 64 + nt * 16 + lrow;
            #pragma unroll
            for (int rr = 0; rr < 4; ++rr) {
                int m = row0 + wr * 64 + mt * 16 + orow + rr;
                if (m < M) C[(size_t)m * Ncol + oc] = (_Float16)acc[mt][nt][rr];
            }
        }
    }
}

static inline void gemm_split(const unsigned short* Ah, const unsigned short* Al,
                              const unsigned short* Bh, const unsigned short* Bl,
                              _Float16* C, int M, int Ncol, int K, hipStream_t st) {
    if (Ncol == 256) {
        int Mb = (M + 127) / 128;
        k_gemm128<<<Mb * 2, 256, 0, st>>>(Ah, Al, Bh, Bl, C, M, Ncol, K);
    } else {
        int Mb = (M + 63) / 64, Nb = (Ncol + 63) / 64;
        k_gemm_split<<<dim3(Mb, Nb), 256, 0, st>>>(Ah, Al, Bh, Bl, C, M, Ncol, K);
    }
}

// ---------------- attention scores: el/er [N,H] ----------------

template <int H, int D>
__global__ __launch_bounds__(256) void k_attn(const _Float16* __restrict__ feat,
                                              const float* __restrict__ al,
                                              const float* __restrict__ ar,
                                              float* __restrict__ el,
                                              float* __restrict__ er, int n) {
    int gw = blockIdx.x * 4 + (threadIdx.x >> 6);
    int lane = threadIdx.x & 63;
    int i = gw / H, h = gw % H;
    if (i >= n) return;
    float f = (lane < D) ? (float)feat[i * (H * D) + h * D + lane] : 0.f;
    float wl = (lane < D) ? al[h * D + lane] : 0.f;
    float wr = (lane < D) ? ar[h * D + lane] : 0.f;
    float pl = f * wl, pr = f * wr;
    #pragma unroll
    for (int off = 32; off; off >>= 1) {
        pl += __shfl_xor(pl, off);
        pr += __shfl_xor(pr, off);
    }
    if (lane == 0) {
        el[i * H + h] = pl;
        er[i * H + h] = pr;
    }
}

__device__ __forceinline__ float lrelu(float v) { return v > 0.f ? v : 0.2f * v; }

// ---------------- H=4 aggregation: ONE WAVE per dst node ------------------
// Online softmax; gather FMA via v_fma_mix_f32 (f16 operand converted inside
// the f32 FMA -> no separate v_cvt chain; bit-exact vs cvt+fma).
template <int ACT, int SPLITOUT>
__global__ __launch_bounds__(256) void k_agg4(const int* __restrict__ rowptr,
                                              const int* __restrict__ csr,
                                              const float* __restrict__ el,
                                              const float* __restrict__ er,
                                              const _Float16* __restrict__ feat,
                                              unsigned short* __restrict__ ohi,
                                              unsigned short* __restrict__ olo,
                                              float* __restrict__ ofp, int n) {
    __shared__ int   s_off[4][16];
    __shared__ float s_ex[4][64];
    int w = threadIdx.x >> 6;
    int lane = threadIdx.x & 63;
    int i = blockIdx.x * 4 + w;
    if (i >= n) return;
    int s0 = rowptr[i], s1 = rowptr[i + 1];
    int deg = s1 - s0;
    int eidx = lane >> 2, h = lane & 3;  // exp-stage role
    int hh = lane >> 4;                  // FMA/output-stage head
    float erh = er[i * 4 + h];
    const char* featLane = (const char*)feat + (lane << 3);

    float den = 0.f;
    float a0 = 0.f, a1 = 0.f, a2 = 0.f, a3 = 0.f;

    auto fma_chunk = [&](int cnt) {
        const float* exrow = &s_ex[w][hh << 4];
        int j = 0;
        for (; j + 4 <= cnt; j += 4) {
            int4   oj = *(const int4*)&s_off[w][j];
            float4 xj = *(const float4*)&exrow[j];
            uint2 p0 = *(const uint2*)(featLane + oj.x);
            uint2 p1 = *(const uint2*)(featLane + oj.y);
            uint2 p2 = *(const uint2*)(featLane + oj.z);
            uint2 p3 = *(const uint2*)(featLane + oj.w);
            FMAMIX_LO(a0, p0.x, xj.x); FMAMIX_HI(a1, p0.x, xj.x);
            FMAMIX_LO(a2, p0.y, xj.x); FMAMIX_HI(a3, p0.y, xj.x);
            FMAMIX_LO(a0, p1.x, xj.y); FMAMIX_HI(a1, p1.x, xj.y);
            FMAMIX_LO(a2, p1.y, xj.y); FMAMIX_HI(a3, p1.y, xj.y);
            FMAMIX_LO(a0, p2.x, xj.z); FMAMIX_HI(a1, p2.x, xj.z);
            FMAMIX_LO(a2, p2.y, xj.z); FMAMIX_HI(a3, p2.y, xj.z);
            FMAMIX_LO(a0, p3.x, xj.w); FMAMIX_HI(a1, p3.x, xj.w);
            FMAMIX_LO(a2, p3.y, xj.w); FMAMIX_HI(a3, p3.y, xj.w);
        }
        for (; j < cnt; ++j) {
            int o = s_off[w][j];
            float x = exrow[j];
            uint2 p0 = *(const uint2*)(featLane + o);
            FMAMIX_LO(a0, p0.x, x); FMAMIX_HI(a1, p0.x, x);
            FMAMIX_LO(a2, p0.y, x); FMAMIX_HI(a3, p0.y, x);
        }
    };

    if (deg <= 16) {
        int e = s0 + eidx;
        int s = 0;
        float v = -INFINITY;
        if (e < s1) {
            s = csr[e];
            v = lrelu(el[(s << 2) + h] + erh);
        }
        float m = v;
        #pragma unroll
        for (int off = 4; off < 64; off <<= 1) m = fmaxf(m, __shfl_xor(m, off));
        float ex = (e < s1) ? __expf(v - m) : 0.f;
        den = ex;
        if (h == 0) s_off[w][eidx] = s << 9;
        s_ex[w][(h << 4) + eidx] = ex;
        fma_chunk(deg);
    } else {
        float m = -INFINITY;
        for (int c = s0; c < s1; c += 16) {
            int e = c + eidx;
            int s = 0;
            float v = -INFINITY;
            if (e < s1) {
                s = csr[e];
                v = lrelu(el[(s << 2) + h] + erh);
            }
            float cm = v;
            #pragma unroll
            for (int off = 4; off < 64; off <<= 1) cm = fmaxf(cm, __shfl_xor(cm, off));
            float mn = fmaxf(m, cm);
            float scale = __expf(m - mn);  // exactly 1.0 when max unchanged; 0 on first chunk
            m = mn;
            float ex = (e < s1) ? __expf(v - mn) : 0.f;
            den = den * scale + ex;
            if (h == 0) s_off[w][eidx] = s << 9;
            s_ex[w][(h << 4) + eidx] = ex;
            float scl = __shfl(scale, hh);  // lanes 0..3 hold h=0..3
            a0 *= scl; a1 *= scl; a2 *= scl; a3 *= scl;
            fma_chunk(min(16, s1 - c));
        }
    }
    #pragma unroll
    for (int off = 4; off < 64; off <<= 1) den += __shfl_xor(den, off);
    float d = fmaxf(__shfl(den, hh), 1e-9f);

    float o0 = (deg > 0) ? a0 / d : 0.f;
    float o1 = (deg > 0) ? a1 / d : 0.f;
    float o2 = (deg > 0) ? a2 / d : 0.f;
    float o3 = (deg > 0) ? a3 / d : 0.f;
    if (ACT == 1) {
        o0 = o0 > 0.f ? o0 : (__expf(o0) - 1.f);
        o1 = o1 > 0.f ? o1 : (__expf(o1) - 1.f);
        o2 = o2 > 0.f ? o2 : (__expf(o2) - 1.f);
        o3 = o3 > 0.f ? o3 : (__expf(o3) - 1.f);
    }
    size_t base = (size_t)i * 256 + (lane << 2);
    if (SPLITOUT) {
        ushort4 vh, vl;
        split_bf(o0, vh.x, vl.x);
        split_bf(o1, vh.y, vl.y);
        split_bf(o2, vh.z, vl.z);
        split_bf(o3, vh.w, vl.w);
        *(ushort4*)&ohi[base] = vh;
        *(ushort4*)&olo[base] = vl;
    } else {
        float4 vo = {o0, o1, o2, o3};
        *(float4*)&ofp[base] = vo;
    }
}

// ---------------- H=1 aggregation (online softmax, fma_mix) ----------------

template <int D, int ACT, int SPLITOUT>
__global__ __launch_bounds__(256) void k_agg1(const int* __restrict__ rowptr,
                                              const int* __restrict__ csr,
                                              const float* __restrict__ el,
                                              const float* __restrict__ er,
                                              const _Float16* __restrict__ feat,
                                              unsigned short* __restrict__ ohi,
                                              unsigned short* __restrict__ olo,
                                              float* __restrict__ ofp, int n) {
    __shared__ int   s_off[4][64];
    __shared__ float s_ex[4][64];
    int w = threadIdx.x >> 6;
    int i = blockIdx.x * 4 + w;
    int lane = threadIdx.x & 63;
    if (i >= n) return;
    int s0 = rowptr[i], s1 = rowptr[i + 1];
    int deg = s1 - s0;
    float eri = er[i];
    bool act = lane < D;
    const char* featLane = (const char*)feat + lane * 2;

    float den = 0.f, acc = 0.f;

    auto fma_chunk = [&](int cnt) {
        int j = 0;
        for (; j + 4 <= cnt; j += 4) {
            int4   oj = *(const int4*)&s_off[w][j];
            float4 xj = *(const float4*)&s_ex[w][j];
            unsigned int u0 = act ? (unsigned int)*(const unsigned short*)(featLane + oj.x) : 0u;
            unsigned int u1 = act ? (unsigned int)*(const unsigned short*)(featLane + oj.y) : 0u;
            unsigned int u2 = act ? (unsigned int)*(const unsigned short*)(featLane + oj.z) : 0u;
            unsigned int u3 = act ? (unsigned int)*(const unsigned short*)(featLane + oj.w) : 0u;
            FMAMIX_LO(acc, u0, xj.x);
            FMAMIX_LO(acc, u1, xj.y);
            FMAMIX_LO(acc, u2, xj.z);
            FMAMIX_LO(acc, u3, xj.w);
        }
        for (; j < cnt; ++j) {
            unsigned int u0 = act ? (unsigned int)*(const unsigned short*)(featLane + s_off[w][j]) : 0u;
            float x = s_ex[w][j];
            FMAMIX_LO(acc, u0, x);
        }
    };

    if (deg <= 64) {
        int e = s0 + lane;
        int s = 0;
        float v = -INFINITY;
        if (e < s1) {
            s = csr[e];
            v = lrelu(el[s] + eri);
        }
        float m = v;
        #pragma unroll
        for (int off = 32; off; off >>= 1) m = fmaxf(m, __shfl_xor(m, off));
        float ex = (e < s1) ? __expf(v - m) : 0.f;
        den = ex;
        s_off[w][lane] = s * (D * 2);
        s_ex[w][lane] = ex;
        fma_chunk(deg);
    } else {
        float m = -INFINITY;
        for (int c = s0; c < s1; c += 64) {
            int e = c + lane;
            int s = 0;
            float ex = 0.f;
            float v = -INFINITY;
            if (e < s1) {
                s = csr[e];
                v = lrelu(el[s] + eri);
            }
            float cm = v;
            #pragma unroll
            for (int off = 32; off; off >>= 1) cm = fmaxf(cm, __shfl_xor(cm, off));
            float mn = fmaxf(m, cm);
            float scale = __expf(m - mn);
            m = mn;
            ex = (e < s1) ? __expf(v - mn) : 0.f;
            den = den * scale + ex;
            acc *= scale;
            s_off[w][lane] = s * (D * 2);
            s_ex[w][lane] = ex;
            fma_chunk(min(64, s1 - c));
        }
    }
    #pragma unroll
    for (int off = 32; off; off >>= 1) den += __shfl_xor(den, off);

    float o = (deg > 0) ? acc / fmaxf(den, 1e-9f) : 0.f;
    if (ACT == 1) o = o > 0.f ? o : (__expf(o) - 1.f);
    if (act) {
        if (SPLITOUT) {
            unsigned short oh, ol;
            split_bf(o, oh, ol);
            ohi[(size_t)i * D + lane] = oh;
            olo[(size_t)i * D + lane] = ol;
        } else {
            ofp[(size_t)i * D + lane] = o;
        }
    }
}

// ---------------- launch ----------------

extern "C" void kernel_launch(void* const* d_in, const int* in_sizes, int n_in,
                              void* d_out, int out_size, void* d_ws, size_t ws_size,
                              hipStream_t stream) {
    const float* x    = (const float*)d_in[0];
    const int*   src  = (const int*)d_in[1];
    const int*   dst  = (const int*)d_in[2];
    const float* W00  = (const float*)d_in[3];
    const float* a00l = (const float*)d_in[4];
    const float* a00r = (const float*)d_in[5];
    const float* W01  = (const float*)d_in[6];
    const float* a01l = (const float*)d_in[7];
    const float* a01r = (const float*)d_in[8];
    const float* W0f  = (const float*)d_in[9];
    const float* a0fl = (const float*)d_in[10];
    const float* a0fr = (const float*)d_in[11];
    const float* W10  = (const float*)d_in[12];
    const float* a10l = (const float*)d_in[13];
    const float* a10r = (const float*)d_in[14];
    const float* W1f  = (const float*)d_in[15];
    const float* a1fl = (const float*)d_in[16];
    const float* a1fr = (const float*)d_in[17];
    const float* W1o  = (const float*)d_in[18];
    const float* a1ol = (const float*)d_in[19];
    const float* a1or = (const float*)d_in[20];
    float* out = (float*)d_out;

    const int n = in_sizes[0] / 256;  // 50000
    const int e = in_sizes[1];        // 800000
    const int C = 40;

    char* p = (char*)d_ws;
    auto alloc = [&](size_t bytes) -> void* {
        void* r = (void*)p;
        p += (bytes + 255) & ~(size_t)255;
        return r;
    };
    int*   deg     = (int*)alloc((size_t)n * 4);
    int*   tmp     = (int*)alloc((size_t)n * 4);
    int*   bsum    = (int*)alloc(64 * 4);
    int*   rowptr  = (int*)alloc((size_t)(n + 1) * 4);
    int*   cursor  = (int*)alloc((size_t)n * 4);
    int*   csr     = (int*)alloc((size_t)e * 4);
    float* el      = (float*)alloc((size_t)n * 4 * 4);
    float* er      = (float*)alloc((size_t)n * 4 * 4);
    _Float16* feat = (_Float16*)alloc((size_t)n * 256 * 2 + 256);
    unsigned short* xhi = (unsigned short*)alloc((size_t)n * 256 * 2);
    unsigned short* xlo = (unsigned short*)alloc((size_t)n * 256 * 2);
    unsigned short* hhi = (unsigned short*)alloc((size_t)n * 256 * 2);
    unsigned short* hlo = (unsigned short*)alloc((size_t)n * 256 * 2);
    unsigned short* W00h = (unsigned short*)alloc(256 * 256 * 2);
    unsigned short* W00l = (unsigned short*)alloc(256 * 256 * 2);
    unsigned short* W01h = (unsigned short*)alloc(256 * 64 * 2);
    unsigned short* W01l = (unsigned short*)alloc(256 * 64 * 2);
    unsigned short* W0fh = (unsigned short*)alloc(64 * 40 * 2);
    unsigned short* W0fl = (unsigned short*)alloc(64 * 40 * 2);
    unsigned short* W10h = (unsigned short*)alloc(256 * 256 * 2);
    unsigned short* W10l = (unsigned short*)alloc(256 * 256 * 2);
    unsigned short* W1fh = (unsigned short*)alloc(256 * 64 * 2);
    unsigned short* W1fl = (unsigned short*)alloc(256 * 64 * 2);
    unsigned short* W1oh = (unsigned short*)alloc(64 * 40 * 2);
    unsigned short* W1ol = (unsigned short*)alloc(64 * 40 * 2);

    // ---- CSR build ----
    hipMemsetAsync(deg, 0, (size_t)n * 4, stream);
    k_hist<<<(e + 255) / 256, 256, 0, stream>>>(dst, deg, e);
    int nb = (n + 1023) / 1024;
    k_scan1<<<nb, 1024, 0, stream>>>(deg, tmp, bsum, n);
    k_scan2<<<1, 1, 0, stream>>>(bsum, nb);
    k_scan3<<<(n + 255) / 256, 256, 0, stream>>>(deg, tmp, bsum, rowptr, cursor, n);
    k_scatter<<<(e + 255) / 256, 256, 0, stream>>>(src, dst, cursor, csr, e);

    // ---- casts ----
    int nel = n * 256;
    k_castx<<<(nel / 4 + 255) / 256, 256, 0, stream>>>(x, xhi, xlo, nel / 4);
    k_castw<<<(256 * 256 + 255) / 256, 256, 0, stream>>>(W00, W00h, W00l, 256, 256);
    k_castw<<<(256 * 64 + 255) / 256, 256, 0, stream>>>(W01, W01h, W01l, 256, 64);
    k_castw<<<(64 * 40 + 255) / 256, 256, 0, stream>>>(W0f, W0fh, W0fl, 64, 40);
    k_castw<<<(256 * 256 + 255) / 256, 256, 0, stream>>>(W10, W10h, W10l, 256, 256);
    k_castw<<<(256 * 64 + 255) / 256, 256, 0, stream>>>(W1f, W1fh, W1fl, 256, 64);
    k_castw<<<(64 * 40 + 255) / 256, 256, 0, stream>>>(W1o, W1oh, W1ol, 64, 40);

    int gw4 = (n * 4 + 3) / 4;
    int gw1 = (n + 3) / 4;

    // ---- branch 0 ----
    gemm_split(xhi, xlo, W00h, W00l, feat, n, 256, 256, stream);
    k_attn<4, 64><<<gw4, 256, 0, stream>>>(feat, a00l, a00r, el, er, n);
    k_agg4<1, 1><<<gw1, 256, 0, stream>>>(rowptr, csr, el, er, feat, hhi, hlo, nullptr, n);

    gemm_split(hhi, hlo, W01h, W01l, feat, n, 64, 256, stream);
    k_attn<1, 64><<<gw1, 256, 0, stream>>>(feat, a01l, a01r, el, er, n);
    k_agg1<64, 1, 1><<<gw1, 256, 0, stream>>>(rowptr, csr, el, er, feat, hhi, hlo, nullptr, n);

    gemm_split(hhi, hlo, W0fh, W0fl, feat, n, C, 64, stream);
    k_attn<1, 40><<<gw1, 256, 0, stream>>>(feat, a0fl, a0fr, el, er, n);
    k_agg1<40, 0, 0><<<gw1, 256, 0, stream>>>(rowptr, csr, el, er, feat, nullptr, nullptr, out, n);

    // ---- branch 1 ----
    gemm_split(xhi, xlo, W10h, W10l, feat, n, 256, 256, stream);
    k_attn<4, 64><<<gw4, 256, 0, stream>>>(feat, a10l, a10r, el, er, n);
    k_agg4<1, 1><<<gw1, 256, 0, stream>>>(rowptr, csr, el, er, feat, hhi, hlo, nullptr, n);

    gemm_split(hhi, hlo, W1fh, W1fl, feat, n, 64, 256, stream);
    k_attn<1, 64><<<gw1, 256, 0, stream>>>(feat, a1fl, a1fr, el, er, n);
    k_agg1<64, 0, 1><<<gw1, 256, 0, stream>>>(rowptr, csr, el, er, feat, hhi, hlo, nullptr, n);

    gemm_split(hhi, hlo, W1oh, W1ol, feat, n, C, 64, stream);
    k_attn<1, 40><<<gw1, 256, 0, stream>>>(feat, a1ol, a1or, el, er, n);
    k_agg1<40, 1, 0><<<gw1, 256, 0, stream>>>(rowptr, csr, el, er, feat, nullptr, nullptr,
                                              out + (size_t)n * C, n);
}